// Round 1
// baseline (69.946 us; speedup 1.0000x reference)
//
#include <hip/hip_runtime.h>
#include <math.h>

// MultiObjectPointMatchingLoss: loss = mean_{b,n} || (R_pred[b]-R_gt[b]) @ p[c_b,n] ||
// Shapes (fixed by reference setup): B=1024, C=21, N=4096.
// point_bank is ~1MB -> L2-resident; compute is ~80M fp32 ops -> launch-latency regime.

__device__ __forceinline__ void quat_to_R(float x, float y, float z, float w, float R[9]) {
    R[0] = 1.0f - 2.0f * (y * y + z * z);
    R[1] = 2.0f * (x * y - w * z);
    R[2] = 2.0f * (x * z + w * y);
    R[3] = 2.0f * (x * y + w * z);
    R[4] = 1.0f - 2.0f * (x * x + z * z);
    R[5] = 2.0f * (y * z - w * x);
    R[6] = 2.0f * (x * z - w * y);
    R[7] = 2.0f * (y * z + w * x);
    R[8] = 1.0f - 2.0f * (x * x + y * y);
}

__device__ __forceinline__ float block_reduce_sum(float acc) {
    // wave (64-lane) shuffle reduce
    #pragma unroll
    for (int off = 32; off > 0; off >>= 1)
        acc += __shfl_down(acc, off, 64);
    __shared__ float s[4];
    const int lane = threadIdx.x & 63;
    const int wv   = threadIdx.x >> 6;
    if (lane == 0) s[wv] = acc;
    __syncthreads();
    float r = 0.0f;
    if (threadIdx.x == 0) r = s[0] + s[1] + s[2] + s[3];
    return r;
}

__global__ __launch_bounds__(256) void pm_loss_partials(
    const float* __restrict__ pred_q,
    const float* __restrict__ gt_q,
    const int*   __restrict__ cls,
    const float* __restrict__ bank,
    float*       __restrict__ partials,
    int N)
{
    const int b = blockIdx.x;

    // Block-uniform quats -> D = R_pred - R_gt (computed redundantly per thread; cheap).
    const float px = pred_q[b * 4 + 0], py = pred_q[b * 4 + 1];
    const float pz = pred_q[b * 4 + 2], pw = pred_q[b * 4 + 3];
    const float gx = gt_q[b * 4 + 0],  gy = gt_q[b * 4 + 1];
    const float gz = gt_q[b * 4 + 2],  gw = gt_q[b * 4 + 3];

    float Rp[9], Rg[9], D[9];
    quat_to_R(px, py, pz, pw, Rp);
    quat_to_R(gx, gy, gz, gw, Rg);
    #pragma unroll
    for (int i = 0; i < 9; ++i) D[i] = Rp[i] - Rg[i];

    const int c = cls[b];
    const float* __restrict__ pts = bank + (size_t)c * (size_t)N * 3;

    float acc = 0.0f;
    for (int n = threadIdx.x; n < N; n += blockDim.x) {
        const float p0 = pts[n * 3 + 0];
        const float p1 = pts[n * 3 + 1];
        const float p2 = pts[n * 3 + 2];
        const float d0 = D[0] * p0 + D[1] * p1 + D[2] * p2;
        const float d1 = D[3] * p0 + D[4] * p1 + D[5] * p2;
        const float d2 = D[6] * p0 + D[7] * p1 + D[8] * p2;
        acc += sqrtf(d0 * d0 + d1 * d1 + d2 * d2);
    }

    const float bsum = block_reduce_sum(acc);
    if (threadIdx.x == 0) partials[b] = bsum;
}

__global__ __launch_bounds__(256) void pm_loss_finalize(
    const float* __restrict__ partials,
    float*       __restrict__ out,
    int nb, float scale)
{
    float acc = 0.0f;
    for (int i = threadIdx.x; i < nb; i += 256)
        acc += partials[i];
    const float s = block_reduce_sum(acc);
    if (threadIdx.x == 0) out[0] = s * scale;
}

extern "C" void kernel_launch(void* const* d_in, const int* in_sizes, int n_in,
                              void* d_out, int out_size, void* d_ws, size_t ws_size,
                              hipStream_t stream) {
    const float* pred_q = (const float*)d_in[0];
    const float* gt_q   = (const float*)d_in[1];
    const int*   cls    = (const int*)d_in[2];   // harness delivers integers as int32
    const float* bank   = (const float*)d_in[3];

    const int B = in_sizes[0] / 4;   // 1024
    const int N = 4096;              // fixed by reference setup (bank is C x N x 3)

    float* partials = (float*)d_ws;  // B floats, all written each call (no zero-init needed)

    pm_loss_partials<<<B, 256, 0, stream>>>(pred_q, gt_q, cls, bank, partials, N);

    const float scale = 1.0f / ((float)B * (float)N);
    pm_loss_finalize<<<1, 256, 0, stream>>>(partials, (float*)d_out, B, scale);
}

// Round 3
// 63.982 us; speedup vs baseline: 1.0932x; 1.0932x over previous
//
#include <hip/hip_runtime.h>
#include <math.h>

// MultiObjectPointMatchingLoss: loss = mean_{b,n} || (R_pred[b]-R_gt[b]) @ p[c_b,n] ||
// B=1024, C=21, N=4096. bank = 1MB (L2-resident). Compute ~105 MFLOP -> latency regime.
// R3: same as R2 but with __builtin_amdgcn_sqrtf (HIP-valid raw v_sqrt_f32).

__device__ __forceinline__ void quat_to_R(float x, float y, float z, float w, float R[9]) {
    R[0] = 1.0f - 2.0f * (y * y + z * z);
    R[1] = 2.0f * (x * y - w * z);
    R[2] = 2.0f * (x * z + w * y);
    R[3] = 2.0f * (x * y + w * z);
    R[4] = 1.0f - 2.0f * (x * x + z * z);
    R[5] = 2.0f * (y * z - w * x);
    R[6] = 2.0f * (x * z - w * y);
    R[7] = 2.0f * (y * z + w * x);
    R[8] = 1.0f - 2.0f * (x * x + y * y);
}

__device__ __forceinline__ float block_reduce_sum_256(float acc) {
    #pragma unroll
    for (int off = 32; off > 0; off >>= 1)
        acc += __shfl_down(acc, off, 64);
    __shared__ float s[4];
    const int lane = threadIdx.x & 63;
    const int wv   = threadIdx.x >> 6;
    if (lane == 0) s[wv] = acc;
    __syncthreads();
    float r = 0.0f;
    if (threadIdx.x == 0) r = s[0] + s[1] + s[2] + s[3];
    return r;
}

__device__ __forceinline__ float norm3(const float D[9], float p0, float p1, float p2) {
    const float d0 = D[0] * p0 + D[1] * p1 + D[2] * p2;
    const float d1 = D[3] * p0 + D[4] * p1 + D[5] * p2;
    const float d2 = D[6] * p0 + D[7] * p1 + D[8] * p2;
    return __builtin_amdgcn_sqrtf(d0 * d0 + d1 * d1 + d2 * d2);
}

__global__ __launch_bounds__(256) void pm_loss_partials(
    const float* __restrict__ pred_q,
    const float* __restrict__ gt_q,
    const int*   __restrict__ cls,
    const float* __restrict__ bank,
    float*       __restrict__ partials,
    int N)
{
    const int b = blockIdx.x;

    const float px = pred_q[b * 4 + 0], py = pred_q[b * 4 + 1];
    const float pz = pred_q[b * 4 + 2], pw = pred_q[b * 4 + 3];
    const float gx = gt_q[b * 4 + 0],  gy = gt_q[b * 4 + 1];
    const float gz = gt_q[b * 4 + 2],  gw = gt_q[b * 4 + 3];

    float Rp[9], Rg[9], D[9];
    quat_to_R(px, py, pz, pw, Rp);
    quat_to_R(gx, gy, gz, gw, Rg);
    #pragma unroll
    for (int i = 0; i < 9; ++i) D[i] = Rp[i] - Rg[i];

    const int c = cls[b];
    const float* __restrict__ pts = bank + (size_t)c * (size_t)N * 3;

    const int t = threadIdx.x;
    float acc = 0.0f;

    // 4 points per thread per iteration: 3x float4 = 48B contiguous per lane.
    const int ptsPerIter = blockDim.x * 4;           // 1024
    const int nAligned   = (N / ptsPerIter) * ptsPerIter;
    for (int i = 0; i < nAligned; i += ptsPerIter) {
        const int n0 = i + t * 4;
        const float4* __restrict__ p4 = (const float4*)(pts + (size_t)n0 * 3);
        const float4 a = p4[0];
        const float4 v = p4[1];
        const float4 c4 = p4[2];
        acc += norm3(D, a.x, a.y, a.z);
        acc += norm3(D, a.w, v.x, v.y);
        acc += norm3(D, v.z, v.w, c4.x);
        acc += norm3(D, c4.y, c4.z, c4.w);
    }
    // tail (not taken for N=4096)
    for (int n = nAligned + t; n < N; n += blockDim.x) {
        acc += norm3(D, pts[n * 3 + 0], pts[n * 3 + 1], pts[n * 3 + 2]);
    }

    const float bsum = block_reduce_sum_256(acc);
    if (threadIdx.x == 0) partials[b] = bsum;
}

__global__ __launch_bounds__(256) void pm_loss_finalize(
    const float* __restrict__ partials,
    float*       __restrict__ out,
    int nb, float scale)
{
    float acc = 0.0f;
    const int nb4 = nb / 4;
    const float4* __restrict__ p4 = (const float4*)partials;
    for (int i = threadIdx.x; i < nb4; i += 256) {
        const float4 v = p4[i];
        acc += (v.x + v.y) + (v.z + v.w);
    }
    for (int i = nb4 * 4 + threadIdx.x; i < nb; i += 256)
        acc += partials[i];
    const float s = block_reduce_sum_256(acc);
    if (threadIdx.x == 0) out[0] = s * scale;
}

extern "C" void kernel_launch(void* const* d_in, const int* in_sizes, int n_in,
                              void* d_out, int out_size, void* d_ws, size_t ws_size,
                              hipStream_t stream) {
    const float* pred_q = (const float*)d_in[0];
    const float* gt_q   = (const float*)d_in[1];
    const int*   cls    = (const int*)d_in[2];
    const float* bank   = (const float*)d_in[3];

    const int B = in_sizes[0] / 4;           // 1024
    const int N = in_sizes[3] / (21 * 3);    // 4096 (C=21 fixed by reference)

    float* partials = (float*)d_ws;          // B floats, fully written each call

    pm_loss_partials<<<B, 256, 0, stream>>>(pred_q, gt_q, cls, bank, partials, N);

    const float scale = 1.0f / ((float)B * (float)N);
    pm_loss_finalize<<<1, 256, 0, stream>>>(partials, (float*)d_out, B, scale);
}